// Round 1
// baseline (1458.567 us; speedup 1.0000x reference)
//
#include <hip/hip_runtime.h>

typedef _Float16 half8 __attribute__((ext_vector_type(8)));
typedef float floatx4 __attribute__((ext_vector_type(4)));
typedef float floatx2 __attribute__((ext_vector_type(2)));

#define N_IN   128
#define N_HID  1024
#define N_OUT  64
#define BB     128
#define TT     256

#define WHH_STRIDE 1032   // 1024 + 8 halves pad
#define WIN_STRIDE 136    // 128 + 8
#define RED_STRIDE 33

__device__ __forceinline__ float tanh_fast(float v) {
    float e = __expf(2.0f * v);
    return 1.0f - 2.0f / (e + 1.0f);
}

// Persistent sequential RNN kernel, fence-free sync protocol.
// Grid: 256 blocks = 8 batch-groups (16 rows) x 32 hidden-slices (32 cols).
// All cross-block traffic (act/h exchange + flags) uses relaxed AGENT-scope
// atomics -> coherent at MALL, works for ANY block->XCD placement.
// NEW vs previous version:
//  * h (fp16) is exchanged alongside tanh(h): each block computes its 2
//    output columns of out = h @ W_out^T with 8 extra MFMAs/wave, reduced
//    via red2 under the existing barrier -> out_gemm kernel DELETED.
//  * x_t loads are issued BEFORE the flag spin (HBM latency hides in wait).
//  * hidden_list store moved AFTER the flag store (out of drain window).
//  * s_sleep removed from the spin (faster detect).
__global__ __launch_bounds__(256, 1) void rnn_seq_kernel(
    const float* __restrict__ x,        // [128][256][128]
    const float* __restrict__ h0,       // [128][1024]
    const float* __restrict__ w_in,     // [1024][128]
    const float* __restrict__ w_hh,     // [1024][1024]
    const float* __restrict__ w_hh_b,   // [1024]
    const float* __restrict__ w_out,    // [64][1024]
    const float* __restrict__ alpha,    // [1024]
    const float* __restrict__ noise_raw,// [128][1024]
    const int* __restrict__ pt_ptr,     // scalar
    float* __restrict__ out,            // hidden_list | output_list | h_final
    _Float16* __restrict__ actbuf,      // d_ws: 2 x [128][1024] fp16 parity buffers (tanh(h))
    _Float16* __restrict__ hbuf,        // d_ws: 2 x [128][1024] fp16 parity buffers (h)
    unsigned int* __restrict__ flags)   // d_ws: [257][8][32] token flags (no init needed)
{
    __shared__ _Float16 Whh_hi[32 * WHH_STRIDE];
    __shared__ _Float16 Whh_lo[32 * WHH_STRIDE];
    __shared__ _Float16 Win_hi[32 * WIN_STRIDE];
    __shared__ _Float16 Win_lo[32 * WIN_STRIDE];
    __shared__ float red[4 * 16 * RED_STRIDE];
    __shared__ float red2[4 * 16 * 2];   // out-GEMM cross-wave partials

    const int tid  = threadIdx.x;
    const int bid  = blockIdx.x;
    const int g    = bid & 7;    // batch group
    const int s    = bid >> 3;   // hidden slice
    const int w    = tid >> 6;   // wave 0..3 (K-split)
    const int lane = tid & 63;
    const int quad = lane >> 4;
    const int mrow = lane & 15;

    // ---- stage W_hh slice rows [32s, 32s+32) as split fp16 hi + lo*1024 ----
    for (int p = 0; p < 32; ++p) {
        int f4 = tid + (p << 8);
        int c  = f4 >> 8;
        int k4 = (f4 & 255) << 2;
        floatx4 wv = *(const floatx4*)(w_hh + ((size_t)(s * 32 + c) << 10) + k4);
        #pragma unroll
        for (int i = 0; i < 4; ++i) {
            float v = wv[i];
            _Float16 hi = (_Float16)v;
            _Float16 lo = (_Float16)((v - (float)hi) * 1024.0f);
            Whh_hi[c * WHH_STRIDE + k4 + i] = hi;
            Whh_lo[c * WHH_STRIDE + k4 + i] = lo;
        }
    }
    for (int p = 0; p < 4; ++p) {
        int f4 = tid + (p << 8);
        int c  = f4 >> 5;
        int k4 = (f4 & 31) << 2;
        floatx4 wv = *(const floatx4*)(w_in + ((size_t)(s * 32 + c) << 7) + k4);
        #pragma unroll
        for (int i = 0; i < 4; ++i) {
            float v = wv[i];
            _Float16 hi = (_Float16)v;
            _Float16 lo = (_Float16)((v - (float)hi) * 1024.0f);
            Win_hi[c * WIN_STRIDE + k4 + i] = hi;
            Win_lo[c * WIN_STRIDE + k4 + i] = lo;
        }
    }
    __syncthreads();

    // ---- load this lane's B-fragments into registers (LDS never re-read) ----
    half8 bh0[8], bl0[8], bh1[8], bl1[8];
    #pragma unroll
    for (int kc = 0; kc < 8; ++kc) {
        int kb = (w << 8) + (kc << 5) + (quad << 3);
        bh0[kc] = *(const half8*)&Whh_hi[mrow * WHH_STRIDE + kb];
        bl0[kc] = *(const half8*)&Whh_lo[mrow * WHH_STRIDE + kb];
        bh1[kc] = *(const half8*)&Whh_hi[(16 + mrow) * WHH_STRIDE + kb];
        bl1[kc] = *(const half8*)&Whh_lo[(16 + mrow) * WHH_STRIDE + kb];
    }
    half8 wi_h0, wi_l0, wi_h1, wi_l1;
    {
        int kb = (w << 5) + (quad << 3);
        wi_h0 = *(const half8*)&Win_hi[mrow * WIN_STRIDE + kb];
        wi_l0 = *(const half8*)&Win_lo[mrow * WIN_STRIDE + kb];
        wi_h1 = *(const half8*)&Win_hi[(16 + mrow) * WIN_STRIDE + kb];
        wi_l1 = *(const half8*)&Win_lo[(16 + mrow) * WIN_STRIDE + kb];
    }

    // ---- W_out B-fragments: block owns out cols {2s, 2s+1} (lanes mrow<2) ----
    half8 wo[8];
    if (mrow < 2) {
        const float* wp = w_out + ((size_t)(s * 2 + mrow) << 10) + (w << 8) + (quad << 3);
        #pragma unroll
        for (int kc = 0; kc < 8; ++kc) {
            floatx4 a0 = *(const floatx4*)(wp + (kc << 5));
            floatx4 a1 = *(const floatx4*)(wp + (kc << 5) + 4);
            #pragma unroll
            for (int i = 0; i < 4; ++i) { wo[kc][i] = (_Float16)a0[i]; wo[kc][4 + i] = (_Float16)a1[i]; }
        }
    } else {
        #pragma unroll
        for (int kc = 0; kc < 8; ++kc) {
            #pragma unroll
            for (int i = 0; i < 8; ++i) wo[kc][i] = (_Float16)0.0f;
        }
    }

    // ---- per-thread owned state: row b, two adjacent cols j0,j0+1 ----
    const int r   = tid >> 4;          // 0..15 group-row
    const int c2  = tid & 15;          // col pair
    const int b   = g * 16 + r;
    const int j0  = s * 32 + 2 * c2;
    const floatx2 a2  = *(const floatx2*)&alpha[j0];
    const floatx2 bi2 = *(const floatx2*)&w_hh_b[j0];
    const floatx2 nr2 = *(const floatx2*)&noise_raw[((size_t)b << 10) + j0];
    const float n0 = nr2.x * 0.05f * __builtin_sqrtf(a2.x);
    const float n1 = nr2.y * 0.05f * __builtin_sqrtf(a2.y);
    const int pt = *pt_ptr;
    floatx2 h2 = *(const floatx2*)&h0[((size_t)b << 10) + j0];
    float hA = h2.x, hB = h2.y;

    // act_{-1} = tanh(h0), h_{-1} = h0 into parity-1 buffers (coherent store)
    {
        unsigned int* act1_32 = (unsigned int*)(actbuf + BB * N_HID);
        unsigned int* h1_32   = (unsigned int*)(hbuf   + BB * N_HID);
        union { _Float16 h[2]; unsigned int u; } pk, pk2;
        pk.h[0]  = (_Float16)tanh_fast(hA);
        pk.h[1]  = (_Float16)tanh_fast(hB);
        pk2.h[0] = (_Float16)hA;
        pk2.h[1] = (_Float16)hB;
        const unsigned idx = (((unsigned)b << 10) + j0) >> 1;
        __hip_atomic_store(&act1_32[idx], pk.u,  __ATOMIC_RELAXED, __HIP_MEMORY_SCOPE_AGENT);
        __hip_atomic_store(&h1_32[idx],   pk2.u, __ATOMIC_RELAXED, __HIP_MEMORY_SCOPE_AGENT);
    }
    __syncthreads();   // emits s_waitcnt vmcnt(0) -> all exchange stores complete
    if (tid == 0)
        __hip_atomic_store(&flags[((unsigned)g) * 32u + s], 1u,
                           __ATOMIC_RELAXED, __HIP_MEMORY_SCOPE_AGENT);

    float* hidden_list = out;
    float* output_list = out + (size_t)BB * TT * N_HID;
    float* h_final = out + (size_t)BB * TT * N_HID + (size_t)BB * TT * N_OUT;
    const int arow = g * 16 + mrow;    // A-fragment batch row for this lane

    for (int t = 0; t < TT; ++t) {
        // ---- x_t prefetch: issue BEFORE the spin, completes during the wait ----
        const float* xp = x + (((size_t)arow << 8) + t) * N_IN + (w << 5) + (quad << 3);
        floatx4 xf0 = *(const floatx4*)xp;
        floatx4 xf1 = *(const floatx4*)(xp + 4);

        // ---- wave w waits only for its 8 producer slices [8w, 8w+8) ----
        {
            const unsigned tok = (unsigned)t + 1u;
            const unsigned fidx = ((unsigned)t * 8u + g) * 32u + (w << 3) + (lane & 7);
            while (true) {
                unsigned v = __hip_atomic_load(&flags[fidx], __ATOMIC_RELAXED,
                                               __HIP_MEMORY_SCOPE_AGENT);
                if (__ballot(v == tok) == ~0ull) break;
            }
        }

        // A fragments: activations (coherent 8B loads), k in [w*256, w*256+256)
        half8 afr[8];
        {
            const unsigned long long* actq = (const unsigned long long*)
                (actbuf + (size_t)((t & 1) ^ 1) * (BB * N_HID));
            const unsigned long long* p =
                actq + ((((size_t)arow << 10) + (w << 8) + (quad << 3)) >> 2);
            #pragma unroll
            for (int kc = 0; kc < 8; ++kc) {
                union { unsigned long long u[2]; half8 h; } cv;
                cv.u[0] = __hip_atomic_load(p + kc * 8,     __ATOMIC_RELAXED,
                                            __HIP_MEMORY_SCOPE_AGENT);
                cv.u[1] = __hip_atomic_load(p + kc * 8 + 1, __ATOMIC_RELAXED,
                                            __HIP_MEMORY_SCOPE_AGENT);
                afr[kc] = cv.h;
            }
        }
        // A fragments: h_t (for out[·,t-1] = h_t @ W_out^T), same layout
        half8 hfr[8];
        {
            const unsigned long long* hq = (const unsigned long long*)
                (hbuf + (size_t)((t & 1) ^ 1) * (BB * N_HID));
            const unsigned long long* p =
                hq + ((((size_t)arow << 10) + (w << 8) + (quad << 3)) >> 2);
            #pragma unroll
            for (int kc = 0; kc < 8; ++kc) {
                union { unsigned long long u[2]; half8 h; } cv;
                cv.u[0] = __hip_atomic_load(p + kc * 8,     __ATOMIC_RELAXED,
                                            __HIP_MEMORY_SCOPE_AGENT);
                cv.u[1] = __hip_atomic_load(p + kc * 8 + 1, __ATOMIC_RELAXED,
                                            __HIP_MEMORY_SCOPE_AGENT);
                hfr[kc] = cv.h;
            }
        }
        // A fragment: x_t (prefetched floats -> fp16)
        half8 xfr;
        #pragma unroll
        for (int i = 0; i < 4; ++i) { xfr[i] = (_Float16)xf0[i]; xfr[4 + i] = (_Float16)xf1[i]; }

        floatx4 acch0 = {0.f,0.f,0.f,0.f}, acch1 = {0.f,0.f,0.f,0.f};
        floatx4 accl0 = {0.f,0.f,0.f,0.f}, accl1 = {0.f,0.f,0.f,0.f};

        acch0 = __builtin_amdgcn_mfma_f32_16x16x32_f16(xfr, wi_h0, acch0, 0, 0, 0);
        accl0 = __builtin_amdgcn_mfma_f32_16x16x32_f16(xfr, wi_l0, accl0, 0, 0, 0);
        acch1 = __builtin_amdgcn_mfma_f32_16x16x32_f16(xfr, wi_h1, acch1, 0, 0, 0);
        accl1 = __builtin_amdgcn_mfma_f32_16x16x32_f16(xfr, wi_l1, accl1, 0, 0, 0);

        #pragma unroll
        for (int kc = 0; kc < 8; ++kc) {
            acch0 = __builtin_amdgcn_mfma_f32_16x16x32_f16(afr[kc], bh0[kc], acch0, 0, 0, 0);
            accl0 = __builtin_amdgcn_mfma_f32_16x16x32_f16(afr[kc], bl0[kc], accl0, 0, 0, 0);
            acch1 = __builtin_amdgcn_mfma_f32_16x16x32_f16(afr[kc], bh1[kc], acch1, 0, 0, 0);
            accl1 = __builtin_amdgcn_mfma_f32_16x16x32_f16(afr[kc], bl1[kc], accl1, 0, 0, 0);
        }

        // out-GEMM partials: D[row][col] valid for col=mrow in {0,1}
        floatx4 aco = {0.f,0.f,0.f,0.f};
        #pragma unroll
        for (int kc = 0; kc < 8; ++kc)
            aco = __builtin_amdgcn_mfma_f32_16x16x32_f16(hfr[kc], wo[kc], aco, 0, 0, 0);

        // cross-wave partials (D layout: row=quad*4+rr, col=lane&15)
        #pragma unroll
        for (int rr = 0; rr < 4; ++rr) {
            red[(w * 16 + quad * 4 + rr) * RED_STRIDE + mrow]
                = acch0[rr] + accl0[rr] * (1.0f / 1024.0f);
            red[(w * 16 + quad * 4 + rr) * RED_STRIDE + 16 + mrow]
                = acch1[rr] + accl1[rr] * (1.0f / 1024.0f);
        }
        if (mrow < 2) {
            #pragma unroll
            for (int rr = 0; rr < 4; ++rr)
                red2[(w * 16 + quad * 4 + rr) * 2 + mrow] = aco[rr];
        }
        __syncthreads();

        // reduce 4 wave-partials, leaky update, noise, stores
        float t0v = bi2.x, t1v = bi2.y;
        #pragma unroll
        for (int ww = 0; ww < 4; ++ww) {
            t0v += red[(ww * 16 + r) * RED_STRIDE + 2 * c2];
            t1v += red[(ww * 16 + r) * RED_STRIDE + 2 * c2 + 1];
        }
        // out[·, t-1] reduce + store (32 values per block)
        if (t > 0 && tid < 32) {
            int rr_ = tid >> 1, oc2 = tid & 1;
            float v = red2[(rr_) * 2 + oc2] + red2[(16 + rr_) * 2 + oc2]
                    + red2[(32 + rr_) * 2 + oc2] + red2[(48 + rr_) * 2 + oc2];
            output_list[((size_t)(g * 16 + rr_) * TT + (t - 1)) * 64 + s * 2 + oc2] = v;
        }

        hA = (1.0f - a2.x) * hA + a2.x * t0v;
        hB = (1.0f - a2.y) * hB + a2.y * t1v;
        if (t == pt) { hA += n0; hB += n1; }

        // exchange stores first (only these gate the flag)
        {
            union { _Float16 h[2]; unsigned int u; } pk, pk2;
            pk.h[0]  = (_Float16)tanh_fast(hA);
            pk.h[1]  = (_Float16)tanh_fast(hB);
            pk2.h[0] = (_Float16)hA;
            pk2.h[1] = (_Float16)hB;
            unsigned int* actw32 = (unsigned int*)(actbuf + (size_t)(t & 1) * (BB * N_HID));
            unsigned int* hw32   = (unsigned int*)(hbuf   + (size_t)(t & 1) * (BB * N_HID));
            const unsigned idx = (((unsigned)b << 10) + j0) >> 1;
            __hip_atomic_store(&actw32[idx], pk.u,  __ATOMIC_RELAXED, __HIP_MEMORY_SCOPE_AGENT);
            __hip_atomic_store(&hw32[idx],   pk2.u, __ATOMIC_RELAXED, __HIP_MEMORY_SCOPE_AGENT);
        }

        __syncthreads();   // drains vmcnt: exchange stores complete before flag store
        if (tid == 0)
            __hip_atomic_store(&flags[((unsigned)(t + 1) * 8u + g) * 32u + s],
                               (unsigned)t + 2u,
                               __ATOMIC_RELAXED, __HIP_MEMORY_SCOPE_AGENT);

        // hidden_list store AFTER the flag: off the drain critical path
        floatx2 hv = {hA, hB};
        *(floatx2*)&hidden_list[(((size_t)b << 8) + t) * N_HID + j0] = hv;
    }

    *(floatx2*)&h_final[((size_t)b << 10) + j0] = (floatx2){hA, hB};

    // ---- epilogue: out[·, TT-1] = h_TT @ W_out^T (one more sync round) ----
    {
        const unsigned tok = (unsigned)TT + 1u;
        const unsigned fidx = ((unsigned)TT * 8u + g) * 32u + (w << 3) + (lane & 7);
        while (true) {
            unsigned v = __hip_atomic_load(&flags[fidx], __ATOMIC_RELAXED,
                                           __HIP_MEMORY_SCOPE_AGENT);
            if (__ballot(v == tok) == ~0ull) break;
        }
    }
    {
        half8 hfr[8];
        const unsigned long long* hq = (const unsigned long long*)
            (hbuf + (size_t)((TT & 1) ^ 1) * (BB * N_HID));
        const unsigned long long* p =
            hq + ((((size_t)arow << 10) + (w << 8) + (quad << 3)) >> 2);
        #pragma unroll
        for (int kc = 0; kc < 8; ++kc) {
            union { unsigned long long u[2]; half8 h; } cv;
            cv.u[0] = __hip_atomic_load(p + kc * 8,     __ATOMIC_RELAXED,
                                        __HIP_MEMORY_SCOPE_AGENT);
            cv.u[1] = __hip_atomic_load(p + kc * 8 + 1, __ATOMIC_RELAXED,
                                        __HIP_MEMORY_SCOPE_AGENT);
            hfr[kc] = cv.h;
        }
        floatx4 aco = {0.f,0.f,0.f,0.f};
        #pragma unroll
        for (int kc = 0; kc < 8; ++kc)
            aco = __builtin_amdgcn_mfma_f32_16x16x32_f16(hfr[kc], wo[kc], aco, 0, 0, 0);
        if (mrow < 2) {
            #pragma unroll
            for (int rr = 0; rr < 4; ++rr)
                red2[(w * 16 + quad * 4 + rr) * 2 + mrow] = aco[rr];
        }
        __syncthreads();
        if (tid < 32) {
            int rr_ = tid >> 1, oc2 = tid & 1;
            float v = red2[(rr_) * 2 + oc2] + red2[(16 + rr_) * 2 + oc2]
                    + red2[(32 + rr_) * 2 + oc2] + red2[(48 + rr_) * 2 + oc2];
            output_list[((size_t)(g * 16 + rr_) * TT + (TT - 1)) * 64 + s * 2 + oc2] = v;
        }
    }
}

extern "C" void kernel_launch(void* const* d_in, const int* in_sizes, int n_in,
                              void* d_out, int out_size, void* d_ws, size_t ws_size,
                              hipStream_t stream)
{
    const float* x      = (const float*)d_in[0];
    const float* h0     = (const float*)d_in[1];
    const float* w_in   = (const float*)d_in[2];
    const float* w_hh   = (const float*)d_in[3];
    const float* w_hh_b = (const float*)d_in[4];
    const float* w_out  = (const float*)d_in[5];
    const float* alpha  = (const float*)d_in[6];
    const float* noise  = (const float*)d_in[7];
    const int*   pt     = (const int*)d_in[8];
    float* out = (float*)d_out;

    // workspace: act parity buffers | h parity buffers | token flags
    _Float16* actbuf = (_Float16*)d_ws;
    _Float16* hbuf   = actbuf + (size_t)2 * BB * N_HID;
    // token-flag array: written once per (t,g,s) with value t+1; 0xAA poison
    // never collides with a token, so NO memset/zeroing is needed.
    unsigned int* flags =
        (unsigned int*)((char*)d_ws + (size_t)4 * BB * N_HID * sizeof(_Float16));

    hipLaunchKernelGGL(rnn_seq_kernel, dim3(256), dim3(256), 0, stream,
                       x, h0, w_in, w_hh, w_hh_b, w_out, alpha, noise, pt, out,
                       actbuf, hbuf, flags);
}

// Round 2
// 1123.064 us; speedup vs baseline: 1.2987x; 1.2987x over previous
//
#include <hip/hip_runtime.h>

typedef _Float16 half8 __attribute__((ext_vector_type(8)));
typedef float floatx4 __attribute__((ext_vector_type(4)));
typedef float floatx2 __attribute__((ext_vector_type(2)));

#define N_IN   128
#define N_HID  1024
#define N_OUT  64
#define BB     128
#define TT     256

#define WHH_STRIDE 1032   // 1024 + 8 halves pad
#define WIN_STRIDE 136    // 128 + 8
#define RED_STRIDE 33
#define HSH_STRIDE 40     // 32 + 8 halves pad (keeps ds_read_b128 16B-aligned)

__device__ __forceinline__ float tanh_fast(float v) {
    float e = __expf(2.0f * v);
    return 1.0f - 2.0f / (e + 1.0f);
}

// Persistent sequential RNN kernel, fence-free sync protocol.
// Grid: 256 blocks = 8 batch-groups (16 rows) x 32 hidden-slices (32 cols).
// All cross-block traffic (act exchange + flags) uses relaxed AGENT-scope
// atomics -> coherent at MALL, works for ANY block->XCD placement.
//
// Output fusion (R2 design): out[b,t,:] = h_t @ W_out^T is computed from
// OWNED state only — each block's 16x32 slice of h_t goes through a tiny
// LDS tile (hsh) into one 16x16x32 MFMA per wave, and the 32 slice-partials
// per out element are summed with device-scope fp32 atomicAdd. ALL of this
// sits AFTER the per-step flag store, i.e. off the inter-block critical
// path (R1's regression came from putting exchange loads / HBM stores /
// extra MFMAs before the drain barrier).
// output_list is zero-initialized in-kernel during init (agent-scope
// stores drained by the init barrier before any token-1 flag, so every
// atomic's target is zeroed before any block can reach its first atomic).
__global__ __launch_bounds__(256, 1) void rnn_seq_kernel(
    const float* __restrict__ x,        // [128][256][128]
    const float* __restrict__ h0,       // [128][1024]
    const float* __restrict__ w_in,     // [1024][128]
    const float* __restrict__ w_hh,     // [1024][1024]
    const float* __restrict__ w_hh_b,   // [1024]
    const float* __restrict__ w_out,    // [64][1024]
    const float* __restrict__ alpha,    // [1024]
    const float* __restrict__ noise_raw,// [128][1024]
    const int* __restrict__ pt_ptr,     // scalar
    float* __restrict__ out,            // hidden_list | output_list | h_final
    _Float16* __restrict__ actbuf,      // d_ws: 2 x [128][1024] fp16 parity buffers (tanh(h))
    unsigned int* __restrict__ flags)   // d_ws: [257][8][32] token flags (no init needed)
{
    __shared__ _Float16 Whh_hi[32 * WHH_STRIDE];
    __shared__ _Float16 Whh_lo[32 * WHH_STRIDE];
    __shared__ _Float16 Win_hi[32 * WIN_STRIDE];
    __shared__ _Float16 Win_lo[32 * WIN_STRIDE];
    __shared__ float red[4 * 16 * RED_STRIDE];
    __shared__ _Float16 hsh[16 * HSH_STRIDE];   // owned h_t slice, fp16

    const int tid  = threadIdx.x;
    const int bid  = blockIdx.x;
    const int g    = bid & 7;    // batch group
    const int s    = bid >> 3;   // hidden slice
    const int w    = tid >> 6;   // wave 0..3 (K-split)
    const int lane = tid & 63;
    const int quad = lane >> 4;
    const int mrow = lane & 15;

    // ---- stage W_hh slice rows [32s, 32s+32) as split fp16 hi + lo*1024 ----
    for (int p = 0; p < 32; ++p) {
        int f4 = tid + (p << 8);
        int c  = f4 >> 8;
        int k4 = (f4 & 255) << 2;
        floatx4 wv = *(const floatx4*)(w_hh + ((size_t)(s * 32 + c) << 10) + k4);
        #pragma unroll
        for (int i = 0; i < 4; ++i) {
            float v = wv[i];
            _Float16 hi = (_Float16)v;
            _Float16 lo = (_Float16)((v - (float)hi) * 1024.0f);
            Whh_hi[c * WHH_STRIDE + k4 + i] = hi;
            Whh_lo[c * WHH_STRIDE + k4 + i] = lo;
        }
    }
    for (int p = 0; p < 4; ++p) {
        int f4 = tid + (p << 8);
        int c  = f4 >> 5;
        int k4 = (f4 & 31) << 2;
        floatx4 wv = *(const floatx4*)(w_in + ((size_t)(s * 32 + c) << 7) + k4);
        #pragma unroll
        for (int i = 0; i < 4; ++i) {
            float v = wv[i];
            _Float16 hi = (_Float16)v;
            _Float16 lo = (_Float16)((v - (float)hi) * 1024.0f);
            Win_hi[c * WIN_STRIDE + k4 + i] = hi;
            Win_lo[c * WIN_STRIDE + k4 + i] = lo;
        }
    }
    __syncthreads();

    // ---- load this lane's B-fragments into registers (LDS never re-read) ----
    half8 bh0[8], bl0[8], bh1[8], bl1[8];
    #pragma unroll
    for (int kc = 0; kc < 8; ++kc) {
        int kb = (w << 8) + (kc << 5) + (quad << 3);
        bh0[kc] = *(const half8*)&Whh_hi[mrow * WHH_STRIDE + kb];
        bl0[kc] = *(const half8*)&Whh_lo[mrow * WHH_STRIDE + kb];
        bh1[kc] = *(const half8*)&Whh_hi[(16 + mrow) * WHH_STRIDE + kb];
        bl1[kc] = *(const half8*)&Whh_lo[(16 + mrow) * WHH_STRIDE + kb];
    }
    half8 wi_h0, wi_l0, wi_h1, wi_l1;
    {
        int kb = (w << 5) + (quad << 3);
        wi_h0 = *(const half8*)&Win_hi[mrow * WIN_STRIDE + kb];
        wi_l0 = *(const half8*)&Win_lo[mrow * WIN_STRIDE + kb];
        wi_h1 = *(const half8*)&Win_hi[(16 + mrow) * WIN_STRIDE + kb];
        wi_l1 = *(const half8*)&Win_lo[(16 + mrow) * WIN_STRIDE + kb];
    }

    // ---- W_out B-fragment: wave w covers out cols [16w,16w+16), K = this
    // block's 32 hidden cols. B layout: col=mrow, k=quad*8+i. 1 half8/lane.
    half8 wo;
    {
        const float* wp = w_out + ((size_t)((w << 4) + mrow) << 10) + (s << 5) + (quad << 3);
        floatx4 a0 = *(const floatx4*)wp;
        floatx4 a1 = *(const floatx4*)(wp + 4);
        #pragma unroll
        for (int i = 0; i < 4; ++i) { wo[i] = (_Float16)a0[i]; wo[4 + i] = (_Float16)a1[i]; }
    }

    // ---- per-thread owned state: row b, two adjacent cols j0,j0+1 ----
    const int r   = tid >> 4;          // 0..15 group-row
    const int c2  = tid & 15;          // col pair
    const int b   = g * 16 + r;
    const int j0  = s * 32 + 2 * c2;
    const floatx2 a2  = *(const floatx2*)&alpha[j0];
    const floatx2 bi2 = *(const floatx2*)&w_hh_b[j0];
    const floatx2 nr2 = *(const floatx2*)&noise_raw[((size_t)b << 10) + j0];
    const float n0 = nr2.x * 0.05f * __builtin_sqrtf(a2.x);
    const float n1 = nr2.y * 0.05f * __builtin_sqrtf(a2.y);
    const int pt = *pt_ptr;
    floatx2 h2 = *(const floatx2*)&h0[((size_t)b << 10) + j0];
    float hA = h2.x, hB = h2.y;

    float* hidden_list = out;
    float* output_list = out + (size_t)BB * TT * N_HID;
    float* h_final = out + (size_t)BB * TT * N_HID + (size_t)BB * TT * N_OUT;

    // act_{-1} = tanh(h0) into parity-1 buffer (coherent store), and
    // zero-init this block's output_list chunk: rows of group g, t in
    // [8s, 8s+8) — disjoint across blocks, 32 KB each, agent-scope so the
    // stores are MALL-coherent for later cross-XCD atomics.
    {
        unsigned int* act1_32 = (unsigned int*)(actbuf + BB * N_HID);
        union { _Float16 h[2]; unsigned int u; } pk;
        pk.h[0] = (_Float16)tanh_fast(hA);
        pk.h[1] = (_Float16)tanh_fast(hB);
        __hip_atomic_store(&act1_32[(((unsigned)b << 10) + j0) >> 1], pk.u,
                           __ATOMIC_RELAXED, __HIP_MEMORY_SCOPE_AGENT);

        unsigned long long* zb = (unsigned long long*)
            (output_list + ((size_t)b * TT + (s << 3)) * 64 + (c2 << 5));
        #pragma unroll
        for (int i = 0; i < 16; ++i)
            __hip_atomic_store(zb + i, 0ull, __ATOMIC_RELAXED,
                               __HIP_MEMORY_SCOPE_AGENT);
    }
    __syncthreads();   // emits s_waitcnt vmcnt(0) -> act + zero stores complete
    if (tid == 0)
        __hip_atomic_store(&flags[((unsigned)g) * 32u + s], 1u,
                           __ATOMIC_RELAXED, __HIP_MEMORY_SCOPE_AGENT);

    const int arow = g * 16 + mrow;    // A-fragment batch row for this lane

    for (int t = 0; t < TT; ++t) {
        // ---- x_t prefetch: issue BEFORE the spin, completes during the wait ----
        const float* xp = x + (((size_t)arow << 8) + t) * N_IN + (w << 5) + (quad << 3);
        floatx4 xf0 = *(const floatx4*)xp;
        floatx4 xf1 = *(const floatx4*)(xp + 4);

        // ---- wave w waits only for its 8 producer slices [8w, 8w+8) ----
        {
            const unsigned tok = (unsigned)t + 1u;
            const unsigned fidx = ((unsigned)t * 8u + g) * 32u + (w << 3) + (lane & 7);
            while (true) {
                unsigned v = __hip_atomic_load(&flags[fidx], __ATOMIC_RELAXED,
                                               __HIP_MEMORY_SCOPE_AGENT);
                if (__ballot(v == tok) == ~0ull) break;
            }
        }

        // A fragments: activations (coherent 8B loads), k in [w*256, w*256+256)
        half8 afr[8];
        {
            const unsigned long long* actq = (const unsigned long long*)
                (actbuf + (size_t)((t & 1) ^ 1) * (BB * N_HID));
            const unsigned long long* p =
                actq + ((((size_t)arow << 10) + (w << 8) + (quad << 3)) >> 2);
            #pragma unroll
            for (int kc = 0; kc < 8; ++kc) {
                union { unsigned long long u[2]; half8 h; } cv;
                cv.u[0] = __hip_atomic_load(p + kc * 8,     __ATOMIC_RELAXED,
                                            __HIP_MEMORY_SCOPE_AGENT);
                cv.u[1] = __hip_atomic_load(p + kc * 8 + 1, __ATOMIC_RELAXED,
                                            __HIP_MEMORY_SCOPE_AGENT);
                afr[kc] = cv.h;
            }
        }
        // A fragment: x_t (prefetched floats -> fp16)
        half8 xfr;
        #pragma unroll
        for (int i = 0; i < 4; ++i) { xfr[i] = (_Float16)xf0[i]; xfr[4 + i] = (_Float16)xf1[i]; }

        floatx4 acch0 = {0.f,0.f,0.f,0.f}, acch1 = {0.f,0.f,0.f,0.f};
        floatx4 accl0 = {0.f,0.f,0.f,0.f}, accl1 = {0.f,0.f,0.f,0.f};

        acch0 = __builtin_amdgcn_mfma_f32_16x16x32_f16(xfr, wi_h0, acch0, 0, 0, 0);
        accl0 = __builtin_amdgcn_mfma_f32_16x16x32_f16(xfr, wi_l0, accl0, 0, 0, 0);
        acch1 = __builtin_amdgcn_mfma_f32_16x16x32_f16(xfr, wi_h1, acch1, 0, 0, 0);
        accl1 = __builtin_amdgcn_mfma_f32_16x16x32_f16(xfr, wi_l1, accl1, 0, 0, 0);

        #pragma unroll
        for (int kc = 0; kc < 8; ++kc) {
            acch0 = __builtin_amdgcn_mfma_f32_16x16x32_f16(afr[kc], bh0[kc], acch0, 0, 0, 0);
            accl0 = __builtin_amdgcn_mfma_f32_16x16x32_f16(afr[kc], bl0[kc], accl0, 0, 0, 0);
            acch1 = __builtin_amdgcn_mfma_f32_16x16x32_f16(afr[kc], bh1[kc], acch1, 0, 0, 0);
            accl1 = __builtin_amdgcn_mfma_f32_16x16x32_f16(afr[kc], bl1[kc], accl1, 0, 0, 0);
        }

        // cross-wave partials (D layout: row=quad*4+rr, col=lane&15)
        #pragma unroll
        for (int rr = 0; rr < 4; ++rr) {
            red[(w * 16 + quad * 4 + rr) * RED_STRIDE + mrow]
                = acch0[rr] + accl0[rr] * (1.0f / 1024.0f);
            red[(w * 16 + quad * 4 + rr) * RED_STRIDE + 16 + mrow]
                = acch1[rr] + accl1[rr] * (1.0f / 1024.0f);
        }
        __syncthreads();

        // reduce 4 wave-partials, leaky update, noise
        float t0v = bi2.x, t1v = bi2.y;
        #pragma unroll
        for (int ww = 0; ww < 4; ++ww) {
            t0v += red[(ww * 16 + r) * RED_STRIDE + 2 * c2];
            t1v += red[(ww * 16 + r) * RED_STRIDE + 2 * c2 + 1];
        }
        hA = (1.0f - a2.x) * hA + a2.x * t0v;
        hB = (1.0f - a2.y) * hB + a2.y * t1v;
        if (t == pt) { hA += n0; hB += n1; }

        // exchange store (the ONLY vmem gating the drain) + owned-h LDS pack
        {
            union { _Float16 h[2]; unsigned int u; } pk, pk2;
            pk.h[0]  = (_Float16)tanh_fast(hA);
            pk.h[1]  = (_Float16)tanh_fast(hB);
            unsigned int* actw32 = (unsigned int*)(actbuf + (size_t)(t & 1) * (BB * N_HID));
            __hip_atomic_store(&actw32[(((unsigned)b << 10) + j0) >> 1], pk.u,
                               __ATOMIC_RELAXED, __HIP_MEMORY_SCOPE_AGENT);
            pk2.h[0] = (_Float16)hA;
            pk2.h[1] = (_Float16)hB;
            ((unsigned int*)hsh)[r * (HSH_STRIDE / 2) + c2] = pk2.u;  // hsh[r][2c2..2c2+1]
        }

        __syncthreads();   // drains vmcnt: act store complete before flag store
        if (tid == 0)
            __hip_atomic_store(&flags[((unsigned)(t + 1) * 8u + g) * 32u + s],
                               (unsigned)t + 2u,
                               __ATOMIC_RELAXED, __HIP_MEMORY_SCOPE_AGENT);

        // ======= everything below is OFF the inter-block critical path =======

        // hidden_list store (drains at next iteration's barrier1, fully hidden)
        floatx2 hv = {hA, hB};
        *(floatx2*)&hidden_list[(((size_t)b << 8) + t) * N_HID + j0] = hv;

        // out partial: A = hsh (16 rows x 32 k, this block's h slice),
        // B = wo (16 out cols x 32 k). D[row=quad*4+rr][col=mrow].
        {
            half8 ha = *(const half8*)&hsh[mrow * HSH_STRIDE + (quad << 3)];
            floatx4 aco = {0.f,0.f,0.f,0.f};
            aco = __builtin_amdgcn_mfma_f32_16x16x32_f16(ha, wo, aco, 0, 0, 0);
            #pragma unroll
            for (int rr = 0; rr < 4; ++rr)
                atomicAdd(&output_list[((size_t)(g * 16 + quad * 4 + rr) * TT + t) * 64
                                       + (w << 4) + mrow], aco[rr]);
        }
    }

    *(floatx2*)&h_final[((size_t)b << 10) + j0] = (floatx2){hA, hB};
}

extern "C" void kernel_launch(void* const* d_in, const int* in_sizes, int n_in,
                              void* d_out, int out_size, void* d_ws, size_t ws_size,
                              hipStream_t stream)
{
    const float* x      = (const float*)d_in[0];
    const float* h0     = (const float*)d_in[1];
    const float* w_in   = (const float*)d_in[2];
    const float* w_hh   = (const float*)d_in[3];
    const float* w_hh_b = (const float*)d_in[4];
    const float* w_out  = (const float*)d_in[5];
    const float* alpha  = (const float*)d_in[6];
    const float* noise  = (const float*)d_in[7];
    const int*   pt     = (const int*)d_in[8];
    float* out = (float*)d_out;

    _Float16* actbuf = (_Float16*)d_ws;
    // token-flag array: written once per (t,g,s) with value t+1; 0xAA poison
    // never collides with a token, so NO memset/zeroing is needed.
    unsigned int* flags =
        (unsigned int*)((char*)d_ws + (size_t)2 * BB * N_HID * sizeof(_Float16));

    hipLaunchKernelGGL(rnn_seq_kernel, dim3(256), dim3(256), 0, stream,
                       x, h0, w_in, w_hh, w_hh_b, w_out, alpha, noise, pt, out,
                       actbuf, flags);
}